// Round 8
// baseline (83.594 us; speedup 1.0000x reference)
//
#include <hip/hip_runtime.h>
#include <hip/hip_bf16.h>

// Problem constants (Atten_tit): B=16, T=256, K=256, H=512, A=49
#define B_ 16
#define T_ 256
#define K_ 256
#define H_ 512
#define A_ 49
#define APAD 64
#define GRID 256
#define WSTR 520   // ushort stride for W LDS rows (+8 pad: 1040B row -> 2-way banks, free)

typedef __attribute__((ext_vector_type(8))) short short8;   // bf16x8
typedef __attribute__((ext_vector_type(4))) float f32x4;

__device__ __forceinline__ ushort f2bf(float f) {
    uint u = __builtin_bit_cast(uint, f);
    u += 0x7FFF + ((u >> 16) & 1);   // RNE
    return (ushort)(u >> 16);
}

// split f32 -> bf16 hi + bf16 lo (residual); hi+lo ~ 17 mantissa bits.
__device__ __forceinline__ void cvt_hilo(float4 v0, float4 v1, short8& hi, short8& lo) {
    float v[8] = {v0.x, v0.y, v0.z, v0.w, v1.x, v1.y, v1.z, v1.w};
    #pragma unroll
    for (int i = 0; i < 8; ++i) {
        ushort h = f2bf(v[i]);
        float hf = __builtin_bit_cast(float, (uint)h << 16);
        hi[i] = (short)h;
        lo[i] = (short)f2bf(v[i] - hf);
    }
}

// 1/(exp(2x)+1); tanh(x) = 1 - 2*sig2(x). exp saturation handles extremes.
__device__ __forceinline__ float sig2(float x) {
    float e = __expf(2.f * x);
    return __builtin_amdgcn_rcpf(e + 1.f);
}

struct SMproj { ushort whi[16][WSTR]; ushort wlo[16][WSTR]; };            // 33280 B
struct SMtr   { float t[4][32][33]; };                                    // 16896 B
struct SMz    { float cg[16][APAD]; float wh[APAD];
                float redM[16][4]; float redS[16][4];
                ushort a[16][K_ + 8]; };                                  // 13312 B
union SMu { SMproj p; SMtr tr; SMz z; };

// ---------------------------------------------------------------------------
// One fused kernel. 256 blocks x 1024 threads, all co-resident.
// P0: blocks [0,128): projection (split-bf16 MFMA, W hi/lo staged in LDS).
//       block = (a-group g = bid&3, 16 tiles starting (bid>>2)*16); 1 tile/wave.
//       tiles 0..255 = des rows -> cvT (B,64,K); 256..511 = title -> cg (B*T,64).
//     blocks [128,256): transpose des (B,K,H) f32 -> desT (B,H,K) bf16,
//       16 32x32 subtiles per block (4 concurrent x 4 iters).
// Grid barrier (agent-scope atomic, counter zeroed by memset each launch).
// P1: z + softmax + PV per (b = bid&15 [XCD-local], t-tile = bid>>4).
__global__ __launch_bounds__(1024) void kFused(const float* __restrict__ des,
                                               const float* __restrict__ title,
                                               const float* __restrict__ Wv,
                                               const float* __restrict__ Wg,
                                               const float* __restrict__ Wh,
                                               float* __restrict__ alpha,
                                               float* __restrict__ chat,
                                               float* __restrict__ cvT,
                                               float* __restrict__ cg,
                                               ushort* __restrict__ desT,
                                               uint* __restrict__ counter)
{
    __shared__ SMu sm;
    int tid = threadIdx.x;
    int bid = blockIdx.x;

    // ================= P0 =================
    if (bid < 128) {
        // ---- projection ----
        int g = bid & 3;
        int tg16 = bid >> 2;              // 0..31
        bool isDes = tg16 < 16;
        const float* W = isDes ? Wv : Wg;

        {   // stage W rows [g*16, g*16+16) as hi/lo bf16 in LDS (rows >=49 zero)
            int row = tid >> 6;           // 0..15
            int c0 = (tid & 63) * 8;      // 0..504
            int a = g * 16 + row;
            float4 v0 = make_float4(0.f,0.f,0.f,0.f), v1 = v0;
            if (a < A_) {
                v0 = *(const float4*)(W + (size_t)a * H_ + c0);
                v1 = *(const float4*)(W + (size_t)a * H_ + c0 + 4);
            }
            short8 hi, lo;
            cvt_hilo(v0, v1, hi, lo);
            *(short8*)&sm.p.whi[row][c0] = hi;
            *(short8*)&sm.p.wlo[row][c0] = lo;
        }
        __syncthreads();

        int wv = tid >> 6, lane = tid & 63;
        int lr = lane & 15, lc = lane >> 4;
        int tile = tg16 * 16 + wv;        // 0..511
        const float* X = isDes ? (des + (size_t)tile * 16 * H_)
                               : (title + (size_t)(tile - 256) * 16 * H_);
        const float* xp0 = X + (size_t)lr * H_ + lc * 8;

        f32x4 acc = {};
        for (int k0 = 0; k0 < H_; k0 += 32) {
            float4 xv0 = *(const float4*)(xp0 + k0);
            float4 xv1 = *(const float4*)(xp0 + k0 + 4);
            short8 xhi, xlo;
            cvt_hilo(xv0, xv1, xhi, xlo);
            short8 whi = *(const short8*)&sm.p.whi[lr][k0 + lc * 8];
            short8 wlo = *(const short8*)&sm.p.wlo[lr][k0 + lc * 8];
            if (isDes) {   // C[a][k-row]
                acc = __builtin_amdgcn_mfma_f32_16x16x32_bf16(whi, xhi, acc, 0, 0, 0);
                acc = __builtin_amdgcn_mfma_f32_16x16x32_bf16(whi, xlo, acc, 0, 0, 0);
                acc = __builtin_amdgcn_mfma_f32_16x16x32_bf16(wlo, xhi, acc, 0, 0, 0);
            } else {       // C[t][a]
                acc = __builtin_amdgcn_mfma_f32_16x16x32_bf16(xhi, whi, acc, 0, 0, 0);
                acc = __builtin_amdgcn_mfma_f32_16x16x32_bf16(xlo, whi, acc, 0, 0, 0);
                acc = __builtin_amdgcn_mfma_f32_16x16x32_bf16(xhi, wlo, acc, 0, 0, 0);
            }
        }

        if (isDes) {
            int krows = tile * 16;
            int b = krows >> 8, kb = krows & 255;
            #pragma unroll
            for (int r = 0; r < 4; ++r) {
                int a = g * 16 + lc * 4 + r;
                cvT[((size_t)b * APAD + a) * K_ + kb + lr] = acc[r];
            }
        } else {
            int trows = (tile - 256) * 16;
            #pragma unroll
            for (int r = 0; r < 4; ++r) {
                int row = trows + lc * 4 + r;
                cg[(size_t)row * APAD + g * 16 + lr] = acc[r];
            }
        }
    } else {
        // ---- transpose: 16 subtiles, 4 concurrent (grp) x 4 iterations ----
        int grp = tid >> 8, st2 = tid & 255;
        int kk = st2 >> 3, c4 = (st2 & 7) * 4;
        #pragma unroll
        for (int it = 0; it < 4; ++it) {
            int st = (bid - 128) * 16 + it * 4 + grp;   // 0..2047
            int b = st >> 7, rem = st & 127;
            int k0 = (rem >> 4) * 32, h0 = (rem & 15) * 32;
            float4 v = *(const float4*)(des + ((size_t)(b * K_ + k0 + kk) * H_) + h0 + c4);
            sm.tr.t[grp][kk][c4 + 0] = v.x;
            sm.tr.t[grp][kk][c4 + 1] = v.y;
            sm.tr.t[grp][kk][c4 + 2] = v.z;
            sm.tr.t[grp][kk][c4 + 3] = v.w;
            __syncthreads();
            ushort4 o;
            o.x = f2bf(sm.tr.t[grp][c4 + 0][kk]);
            o.y = f2bf(sm.tr.t[grp][c4 + 1][kk]);
            o.z = f2bf(sm.tr.t[grp][c4 + 2][kk]);
            o.w = f2bf(sm.tr.t[grp][c4 + 3][kk]);
            *(ushort4*)(desT + ((size_t)(b * H_ + h0 + kk) * K_) + k0 + c4) = o;
            __syncthreads();
        }
    }

    // ================= grid barrier =================
    __syncthreads();
    if (tid == 0) {
        __hip_atomic_fetch_add(counter, 1u, __ATOMIC_ACQ_REL, __HIP_MEMORY_SCOPE_AGENT);
        while (__hip_atomic_load(counter, __ATOMIC_ACQUIRE, __HIP_MEMORY_SCOPE_AGENT) < GRID)
            __builtin_amdgcn_s_sleep(8);
    }
    __syncthreads();

    // ================= P1: z + softmax + PV =================
    int b  = bid & 15;                    // XCD-local b (T1 swizzle)
    int t0 = (bid >> 4) << 4;
    int k  = tid & 255;
    int tg = tid >> 8;                    // 0..3
    int tb = tg * 4;

    if (tid < 256) {
        int row = tid >> 4, c = (tid & 15) * 4;
        *(float4*)(&sm.z.cg[row][c]) =
            *(const float4*)(cg + (size_t)(b * T_ + t0 + row) * APAD + c);
    } else if (tid < 256 + APAD) {
        int a = tid - 256;
        sm.z.wh[a] = (a < A_) ? Wh[a] : 0.f;
    }
    __syncthreads();

    // ---- z phase: 4 t's per thread ----
    float zacc[4] = {0.f, 0.f, 0.f, 0.f};
    float sw = 0.f;
    const float* cvp = cvT + (size_t)b * APAD * K_ + k;

    for (int c = 0; c < 12; ++c) {
        int a0 = c * 4;
        float xa[4];
        #pragma unroll
        for (int i = 0; i < 4; ++i) xa[i] = cvp[(size_t)(a0 + i) * K_];
        float4 w4 = *(const float4*)(&sm.z.wh[a0]);
        sw += w4.x + w4.y + w4.z + w4.w;
        #pragma unroll
        for (int j = 0; j < 4; ++j) {
            float4 cj = *(const float4*)(&sm.z.cg[tb + j][a0]);
            zacc[j] += w4.x * sig2(xa[0] + cj.x)
                     + w4.y * sig2(xa[1] + cj.y)
                     + w4.z * sig2(xa[2] + cj.z)
                     + w4.w * sig2(xa[3] + cj.w);
        }
    }
    {   // tail a = 48
        float xa = cvp[(size_t)48 * K_];
        float wh = sm.z.wh[48];
        sw += wh;
        #pragma unroll
        for (int j = 0; j < 4; ++j)
            zacc[j] += wh * sig2(xa + sm.z.cg[tb + j][48]);
    }
    float z[4];
    #pragma unroll
    for (int j = 0; j < 4; ++j) z[j] = sw - 2.f * zacc[j];

    // ---- softmax over k ----
    int wv = tid >> 6, lane = tid & 63, w3 = wv & 3;
    #pragma unroll
    for (int j = 0; j < 4; ++j) {
        float m = z[j];
        #pragma unroll
        for (int off = 32; off > 0; off >>= 1) m = fmaxf(m, __shfl_xor(m, off));
        if (lane == 0) sm.z.redM[tb + j][w3] = m;
    }
    __syncthreads();
    #pragma unroll
    for (int j = 0; j < 4; ++j) {
        int t = tb + j;
        float m = fmaxf(fmaxf(sm.z.redM[t][0], sm.z.redM[t][1]),
                        fmaxf(sm.z.redM[t][2], sm.z.redM[t][3]));
        z[j] = __expf(z[j] - m);
    }
    #pragma unroll
    for (int j = 0; j < 4; ++j) {
        float s = z[j];
        #pragma unroll
        for (int off = 32; off > 0; off >>= 1) s += __shfl_xor(s, off);
        if (lane == 0) sm.z.redS[tb + j][w3] = s;
    }
    __syncthreads();
    #pragma unroll
    for (int j = 0; j < 4; ++j) {
        int t = tb + j;
        float s = sm.z.redS[t][0] + sm.z.redS[t][1] + sm.z.redS[t][2] + sm.z.redS[t][3];
        float rs = __builtin_amdgcn_rcpf(s);
        rs = rs * (2.f - s * rs);              // Newton step
        float al = z[j] * rs;
        alpha[(size_t)(b * T_ + t0 + t) * K_ + k] = al;
        sm.z.a[t][k] = f2bf(al);
    }
    __syncthreads();

    // ---- PV: wave wv -> h-panel [wv*32, wv*32+32) ----
    int lr = lane & 15, lc = lane >> 4;
    int h0 = wv * 32;
    const ushort* Bp = desT + ((size_t)(b * H_ + h0 + lr)) * K_ + lc * 8;

    f32x4 acc0 = {}, acc1 = {};
    #pragma unroll
    for (int kb = 0; kb < K_; kb += 32) {
        short8 a8 = *(const short8*)(&sm.z.a[lr][kb + lc * 8]);
        short8 b0 = *(const short8*)(Bp + kb);
        short8 b1 = *(const short8*)(Bp + (size_t)16 * K_ + kb);
        acc0 = __builtin_amdgcn_mfma_f32_16x16x32_bf16(a8, b0, acc0, 0, 0, 0);
        acc1 = __builtin_amdgcn_mfma_f32_16x16x32_bf16(a8, b1, acc1, 0, 0, 0);
    }

    #pragma unroll
    for (int r = 0; r < 4; ++r) {
        int row = t0 + lc * 4 + r;
        chat[((size_t)(b * T_ + row)) * H_ + h0 + lr]      = acc0[r];
        chat[((size_t)(b * T_ + row)) * H_ + h0 + 16 + lr] = acc1[r];
    }
}

// ---------------------------------------------------------------------------
extern "C" void kernel_launch(void* const* d_in, const int* in_sizes, int n_in,
                              void* d_out, int out_size, void* d_ws, size_t ws_size,
                              hipStream_t stream) {
    const float* des   = (const float*)d_in[0];
    const float* title = (const float*)d_in[1];
    const float* Wv    = (const float*)d_in[2];
    const float* Wg    = (const float*)d_in[3];
    const float* Wh    = (const float*)d_in[4];

    float* chat  = (float*)d_out;                            // (B,T,H)
    float* alpha = (float*)d_out + (size_t)B_ * T_ * H_;     // (B,T,K)

    char* ws = (char*)d_ws;
    float*  cvT  = (float*)ws;                               // (B,64,K) f32: 1 MB
    float*  cg   = cvT + (size_t)B_ * APAD * K_;             // (B*T,64) f32: 1 MB
    ushort* desT = (ushort*)(cg + (size_t)B_ * T_ * APAD);   // (B,H,K) bf16: 4 MB
    uint* counter = (uint*)(desT + (size_t)B_ * H_ * K_);    // barrier counter

    hipMemsetAsync(counter, 0, 128, stream);                 // graph-safe reset
    hipLaunchKernelGGL(kFused, dim3(GRID), dim3(1024), 0, stream,
                       des, title, Wv, Wg, Wh, alpha, chat, cvT, cg, desT, counter);
}